// Round 1
// baseline (3392.841 us; speedup 1.0000x reference)
//
#include <hip/hip_runtime.h>

#define NN 50000
#define NE 200000
#define NG 512
#define FN 64
#define FE 16
#define FE2 32
#define H 32
#define NL 3
#define EPSV 1e-5f

// ---------------- prep: transpose W_nn[l][k][i][o] -> Wt[l][i][k][o] ----------------
__global__ void k_prep_wt(const float* __restrict__ Wnn, float* __restrict__ Wt) {
    int idx = blockIdx.x * 256 + threadIdx.x;
    if (idx >= NL * FE2 * H * H) return;
    int o = idx & 31;
    int i = (idx >> 5) & 31;
    int k = (idx >> 10) & 31;
    int l = idx >> 15;
    Wt[((l * H + i) * FE2 + k) * H + o] = Wnn[idx];
}

// ---------------- node embedding: h = x @ W_node + b_node ----------------
__global__ void k_node_emb(const float* __restrict__ x, const float* __restrict__ W,
                           const float* __restrict__ b, float* __restrict__ h) {
    __shared__ float sW[FN * H];
    int t = threadIdx.x;
    for (int j = t; j < FN * H; j += 256) sW[j] = W[j];
    __syncthreads();
    int node = blockIdx.x * 8 + (t >> 5);
    int o = t & 31;
    if (node >= NN) return;
    const float* xr = x + node * FN;
    float acc = b[o];
#pragma unroll 16
    for (int i = 0; i < FN; i++) acc += xr[i] * sW[i * H + o];
    h[node * H + o] = acc;
}

// ---------------- edge embedding: ea = edge_attr @ W_edge + b_edge ----------------
__global__ void k_edge_emb(const float* __restrict__ eattr, const float* __restrict__ W,
                           const float* __restrict__ b, float* __restrict__ ea) {
    __shared__ float sW[FE * FE2];
    int t = threadIdx.x;
    for (int j = t; j < FE * FE2; j += 256) sW[j] = W[j];
    __syncthreads();
    int e = blockIdx.x * 8 + (t >> 5);
    int o = t & 31;
    if (e >= NE) return;
    const float* er = eattr + e * FE;
    float acc = b[o];
#pragma unroll
    for (int i = 0; i < FE; i++) acc += er[i] * sW[i * FE2 + o];
    ea[e * FE2 + o] = acc;
}

// ---------------- T = h @ Wt_l   (M=NN, K=32, Ncols=1024) ----------------
// block: 256 threads, tile 32 nodes x 128 cols, each thread 4x4 outputs
__global__ void k_gemm_T(const float* __restrict__ h, const float* __restrict__ Wt,
                         float* __restrict__ T) {
    __shared__ float sh[32][33];
    int t = threadIdx.x;
    int nb = (blockIdx.x >> 3) * 32;
    int cb = (blockIdx.x & 7) * 128;
    for (int j = t; j < 32 * 32; j += 256) {
        int nn = j >> 5, kk = j & 31;
        int node = nb + nn;
        sh[nn][kk] = (node < NN) ? h[node * H + kk] : 0.f;
    }
    __syncthreads();
    int tc = t & 31, tr = t >> 5;
    float acc[4][4] = {};
    const float* wp = Wt + cb + tc * 4;
#pragma unroll
    for (int k = 0; k < 32; k++) {
        float4 w = *(const float4*)(wp + k * 1024);
        float h0 = sh[tr * 4 + 0][k];
        float h1 = sh[tr * 4 + 1][k];
        float h2 = sh[tr * 4 + 2][k];
        float h3 = sh[tr * 4 + 3][k];
        acc[0][0] += h0 * w.x; acc[0][1] += h0 * w.y; acc[0][2] += h0 * w.z; acc[0][3] += h0 * w.w;
        acc[1][0] += h1 * w.x; acc[1][1] += h1 * w.y; acc[1][2] += h1 * w.z; acc[1][3] += h1 * w.w;
        acc[2][0] += h2 * w.x; acc[2][1] += h2 * w.y; acc[2][2] += h2 * w.z; acc[2][3] += h2 * w.w;
        acc[3][0] += h3 * w.x; acc[3][1] += h3 * w.y; acc[3][2] += h3 * w.z; acc[3][3] += h3 * w.w;
    }
#pragma unroll
    for (int r = 0; r < 4; r++) {
        int node = nb + tr * 4 + r;
        if (node < NN) {
            float4 v = make_float4(acc[r][0], acc[r][1], acc[r][2], acc[r][3]);
            *(float4*)(T + (size_t)node * 1024 + cb + tc * 4) = v;
        }
    }
}

// ---------------- node linear: z = h@W_root + b_conv ; u = h@Bnn ----------------
__global__ void k_node_lin(const float* __restrict__ h, const float* __restrict__ Wr,
                           const float* __restrict__ bc, const float* __restrict__ bnn,
                           float* __restrict__ z, float* __restrict__ u) {
    __shared__ float sWr[H * H];
    __shared__ float sBn[H * H];
    int t = threadIdx.x;
    for (int j = t; j < H * H; j += 256) { sWr[j] = Wr[j]; sBn[j] = bnn[j]; }
    __syncthreads();
    int node = blockIdx.x * 8 + (t >> 5);
    int o = t & 31;
    if (node >= NN) return;
    const float* hr = h + node * H;
    float a = bc[o], bacc = 0.f;
#pragma unroll
    for (int i = 0; i < H; i++) {
        float hv = hr[i];
        a += hv * sWr[i * H + o];
        bacc += hv * sBn[i * H + o];
    }
    z[node * H + o] = a;
    u[node * H + o] = bacc;
}

// ---------------- edge message: m = u_src + ea_e . T_src ; atomic into agg[dst] ----------------
__global__ void k_edge_msg(const float* __restrict__ ea, const float* __restrict__ T,
                           const float* __restrict__ u, const int* __restrict__ src,
                           const int* __restrict__ dst, float* __restrict__ agg) {
    __shared__ float sea[8][32];
    int t = threadIdx.x;
    int eb = blockIdx.x * 8;
    for (int j = t; j < 8 * 32; j += 256) {
        int e = eb + (j >> 5);
        if (e < NE) sea[j >> 5][j & 31] = ea[e * FE2 + (j & 31)];
    }
    __syncthreads();
    int e = eb + (t >> 5);
    int o = t & 31;
    if (e >= NE) return;
    int s = src[e], d = dst[e];
    const float* Tr = T + (size_t)s * 1024;
    float m = u[s * H + o];
    const float* sr = sea[t >> 5];
#pragma unroll
    for (int k = 0; k < 32; k++) m += sr[k] * Tr[k * 32 + o];
    atomicAdd(&agg[d * H + o], m);
}

// ---------------- z += agg ; accumulate per-channel sum & sumsq ----------------
__global__ void k_add_stats(float* __restrict__ z, const float* __restrict__ agg,
                            float* __restrict__ stats) {
    __shared__ float red[256];
    int t = threadIdx.x;
    float s = 0.f, s2 = 0.f;
    for (size_t idx = (size_t)blockIdx.x * 256 + t; idx < (size_t)NN * H;
         idx += (size_t)gridDim.x * 256) {
        float v = z[idx] + agg[idx];
        z[idx] = v;
        s += v;
        s2 += v * v;
    }
    red[t] = s;
    __syncthreads();
    for (int st = 128; st >= 32; st >>= 1) {
        if (t < st) red[t] += red[t + st];
        __syncthreads();
    }
    if (t < 32) atomicAdd(&stats[t], red[t]);
    __syncthreads();
    red[t] = s2;
    __syncthreads();
    for (int st = 128; st >= 32; st >>= 1) {
        if (t < st) red[t] += red[t + st];
        __syncthreads();
    }
    if (t < 32) atomicAdd(&stats[32 + t], red[t]);
}

// ---------------- BN apply + ReLU ----------------
__global__ void k_bn_apply(const float* __restrict__ z, const float* __restrict__ stats,
                           const float* __restrict__ gamma, const float* __restrict__ beta,
                           float* __restrict__ h) {
    int idx = blockIdx.x * 256 + threadIdx.x;
    if (idx >= NN * H) return;
    int o = idx & 31;
    const float invn = 1.0f / (float)NN;
    float mu = stats[o] * invn;
    float var = stats[32 + o] * invn - mu * mu;
    float v = (z[idx] - mu) * rsqrtf(var + EPSV) * gamma[o] + beta[o];
    h[idx] = v > 0.f ? v : 0.f;
}

// ---------------- pool: segment sums over graphs ----------------
__global__ void k_pool(const float* __restrict__ h, const int* __restrict__ batch,
                       float* __restrict__ gsum, float* __restrict__ cnt) {
    int idx = blockIdx.x * 256 + threadIdx.x;
    if (idx >= NN * H) return;
    int n = idx >> 5, o = idx & 31;
    int g = batch[n];
    atomicAdd(&gsum[g * H + o], h[idx]);
    if (o == 0) atomicAdd(&cnt[g], 1.f);
}

// ---------------- head: gx -> lin2 -> relu -> lin3 ----------------
__global__ void k_head(const float* __restrict__ gsum, const float* __restrict__ cnt,
                       const float* __restrict__ W2, const float* __restrict__ b2,
                       const float* __restrict__ W3, const float* __restrict__ b3,
                       float* __restrict__ out) {
    __shared__ float sW2[H * 16];
    __shared__ float sW3[16];
    __shared__ float sb2[16];
    int t = threadIdx.x;
    for (int j = t; j < H * 16; j += 256) sW2[j] = W2[j];
    if (t < 16) { sW3[t] = W3[t]; sb2[t] = b2[t]; }
    __syncthreads();
    int g = blockIdx.x * 256 + t;
    if (g >= NG) return;
    float inv = 1.0f / fmaxf(cnt[g], 1.0f);
    float gx[H];
#pragma unroll
    for (int i = 0; i < H; i++) gx[i] = gsum[g * H + i] * inv;
    float o3 = b3[0];
#pragma unroll
    for (int j = 0; j < 16; j++) {
        float hh = sb2[j];
#pragma unroll
        for (int i = 0; i < H; i++) hh += gx[i] * sW2[i * 16 + j];
        hh = hh > 0.f ? hh : 0.f;
        o3 += hh * sW3[j];
    }
    out[g] = o3;
}

extern "C" void kernel_launch(void* const* d_in, const int* in_sizes, int n_in,
                              void* d_out, int out_size, void* d_ws, size_t ws_size,
                              hipStream_t stream) {
    const float* x      = (const float*)d_in[0];
    const float* eattr  = (const float*)d_in[1];
    const float* W_node = (const float*)d_in[2];
    const float* b_node = (const float*)d_in[3];
    const float* W_edge = (const float*)d_in[4];
    const float* b_edge = (const float*)d_in[5];
    const float* W_nn   = (const float*)d_in[6];
    const float* b_nn   = (const float*)d_in[7];
    const float* W_root = (const float*)d_in[8];
    const float* b_conv = (const float*)d_in[9];
    const float* gamma  = (const float*)d_in[10];
    const float* beta   = (const float*)d_in[11];
    const float* W2     = (const float*)d_in[12];
    const float* b2     = (const float*)d_in[13];
    const float* W3     = (const float*)d_in[14];
    const float* b3     = (const float*)d_in[15];
    const int* eidx     = (const int*)d_in[16];
    const int* batch    = (const int*)d_in[17];
    const int* src = eidx;
    const int* dst = eidx + NE;
    float* out = (float*)d_out;

    float* ws = (float*)d_ws;
    float* h    = ws;                       // NN*32
    float* z    = h + (size_t)NN * H;       // NN*32
    float* u    = z + (size_t)NN * H;       // NN*32
    float* agg  = u + (size_t)NN * H;       // NN*32
    float* ea   = agg + (size_t)NN * H;     // NE*32
    float* Wt   = ea + (size_t)NE * FE2;    // 3*32*1024
    float* stats = Wt + (size_t)NL * H * FE2 * H;  // 64
    float* gsum = stats + 64;               // NG*32
    float* cnt  = gsum + (size_t)NG * H;    // NG
    float* T    = cnt + NG;                 // NN*1024

    // prep transposed W_nn
    k_prep_wt<<<(NL * FE2 * H * H + 255) / 256, 256, 0, stream>>>(W_nn, Wt);
    // embeddings
    k_node_emb<<<(NN + 7) / 8, 256, 0, stream>>>(x, W_node, b_node, h);
    k_edge_emb<<<(NE + 7) / 8, 256, 0, stream>>>(eattr, W_edge, b_edge, ea);

    for (int l = 0; l < NL; l++) {
        k_gemm_T<<<((NN + 31) / 32) * 8, 256, 0, stream>>>(h, Wt + (size_t)l * H * FE2 * H, T);
        k_node_lin<<<(NN + 7) / 8, 256, 0, stream>>>(h, W_root + l * H * H, b_conv + l * H,
                                                     b_nn + l * H * H, z, u);
        hipMemsetAsync(agg, 0, (size_t)NN * H * sizeof(float), stream);
        hipMemsetAsync(stats, 0, 64 * sizeof(float), stream);
        k_edge_msg<<<(NE + 7) / 8, 256, 0, stream>>>(ea, T, u, src, dst, agg);
        k_add_stats<<<512, 256, 0, stream>>>(z, agg, stats);
        k_bn_apply<<<(NN * H + 255) / 256, 256, 0, stream>>>(z, stats, gamma + l * H,
                                                             beta + l * H, h);
    }

    hipMemsetAsync(gsum, 0, (size_t)NG * H * sizeof(float), stream);
    hipMemsetAsync(cnt, 0, NG * sizeof(float), stream);
    k_pool<<<(NN * H + 255) / 256, 256, 0, stream>>>(h, batch, gsum, cnt);
    k_head<<<(NG + 255) / 256, 256, 0, stream>>>(gsum, cnt, W2, b2, W3, b3, out);
}

// Round 2
// 3161.182 us; speedup vs baseline: 1.0733x; 1.0733x over previous
//
#include <hip/hip_runtime.h>

#define NN 50000
#define NE 200000
#define NG 512
#define FN 64
#define FE 16
#define FE2 32
#define H 32
#define NL 3
#define EPSV 1e-5f

// ---------------- prep: repack W_nn[l][kf][i*32+o] -> Wt2[l][cb][i][c'] ----------------
// column c = cb*128 + c' indexes the flattened (kf,o) pair: kf = c>>5, o = c&31.
// Wt2 slice [cb] is a contiguous 32x128 (16 KB) block for LDS staging.
__global__ void k_prep_wt(const float* __restrict__ Wnn, float* __restrict__ Wt2) {
    int idx = blockIdx.x * 256 + threadIdx.x;
    if (idx >= NL * 8 * 32 * 128) return;
    int cp = idx & 127;
    int i  = (idx >> 7) & 31;
    int cb = (idx >> 12) & 7;
    int l  = idx >> 15;
    int c  = cb * 128 + cp;
    int kf = c >> 5, o = c & 31;
    Wt2[idx] = Wnn[((size_t)l * 32 + kf) * 1024 + i * 32 + o];
}

// ---------------- node embedding: h = x @ W_node + b_node ----------------
__global__ void k_node_emb(const float* __restrict__ x, const float* __restrict__ W,
                           const float* __restrict__ b, float* __restrict__ h) {
    __shared__ float sW[FN * H];
    int t = threadIdx.x;
    for (int j = t; j < FN * H; j += 256) sW[j] = W[j];
    __syncthreads();
    int node = blockIdx.x * 8 + (t >> 5);
    int o = t & 31;
    if (node >= NN) return;
    const float* xr = x + node * FN;
    float acc = b[o];
#pragma unroll 16
    for (int i = 0; i < FN; i++) acc += xr[i] * sW[i * H + o];
    h[node * H + o] = acc;
}

// ---------------- edge embedding: ea = edge_attr @ W_edge + b_edge ----------------
__global__ void k_edge_emb(const float* __restrict__ eattr, const float* __restrict__ W,
                           const float* __restrict__ b, float* __restrict__ ea) {
    __shared__ float sW[FE * FE2];
    int t = threadIdx.x;
    for (int j = t; j < FE * FE2; j += 256) sW[j] = W[j];
    __syncthreads();
    int e = blockIdx.x * 8 + (t >> 5);
    int o = t & 31;
    if (e >= NE) return;
    const float* er = eattr + e * FE;
    float acc = b[o];
#pragma unroll
    for (int i = 0; i < FE; i++) acc += er[i] * sW[i * FE2 + o];
    ea[e * FE2 + o] = acc;
}

// ---------------- T = h @ Wt_l  (M=NN, K=32, Ncols=1024), pure-LDS inner loop ----------------
// block: 256 threads, tile 32 nodes x 128 cols; Wt slice (16 KB) staged in LDS.
__global__ void k_gemm_T(const float* __restrict__ h, const float* __restrict__ Wt2l,
                         float* __restrict__ T) {
    __shared__ __align__(16) float sh[32][36];   // h tile, padded for float4 reads
    __shared__ float4 sW[32 * 32];               // Wt slice [i][128] as float4 [i][32]
    int t = threadIdx.x;
    int nb = (blockIdx.x >> 3) * 32;
    int cb = blockIdx.x & 7;

    const float4* wsrc = (const float4*)(Wt2l + (size_t)cb * 32 * 128);
    for (int j = t; j < 1024; j += 256) sW[j] = wsrc[j];
    for (int j = t; j < 1024; j += 256) {
        int nn = j >> 5, kk = j & 31;
        int node = nb + nn;
        sh[nn][kk] = (node < NN) ? h[node * H + kk] : 0.f;
    }
    __syncthreads();

    int tc = t & 31, tr = t >> 5;
    float acc[4][4] = {};
#pragma unroll
    for (int kk = 0; kk < 32; kk += 4) {
        float4 h0 = *(const float4*)&sh[tr * 4 + 0][kk];
        float4 h1 = *(const float4*)&sh[tr * 4 + 1][kk];
        float4 h2 = *(const float4*)&sh[tr * 4 + 2][kk];
        float4 h3 = *(const float4*)&sh[tr * 4 + 3][kk];
        float4 w;
        w = sW[(kk + 0) * 32 + tc];
        acc[0][0] += h0.x * w.x; acc[0][1] += h0.x * w.y; acc[0][2] += h0.x * w.z; acc[0][3] += h0.x * w.w;
        acc[1][0] += h1.x * w.x; acc[1][1] += h1.x * w.y; acc[1][2] += h1.x * w.z; acc[1][3] += h1.x * w.w;
        acc[2][0] += h2.x * w.x; acc[2][1] += h2.x * w.y; acc[2][2] += h2.x * w.z; acc[2][3] += h2.x * w.w;
        acc[3][0] += h3.x * w.x; acc[3][1] += h3.x * w.y; acc[3][2] += h3.x * w.z; acc[3][3] += h3.x * w.w;
        w = sW[(kk + 1) * 32 + tc];
        acc[0][0] += h0.y * w.x; acc[0][1] += h0.y * w.y; acc[0][2] += h0.y * w.z; acc[0][3] += h0.y * w.w;
        acc[1][0] += h1.y * w.x; acc[1][1] += h1.y * w.y; acc[1][2] += h1.y * w.z; acc[1][3] += h1.y * w.w;
        acc[2][0] += h2.y * w.x; acc[2][1] += h2.y * w.y; acc[2][2] += h2.y * w.z; acc[2][3] += h2.y * w.w;
        acc[3][0] += h3.y * w.x; acc[3][1] += h3.y * w.y; acc[3][2] += h3.y * w.z; acc[3][3] += h3.y * w.w;
        w = sW[(kk + 2) * 32 + tc];
        acc[0][0] += h0.z * w.x; acc[0][1] += h0.z * w.y; acc[0][2] += h0.z * w.z; acc[0][3] += h0.z * w.w;
        acc[1][0] += h1.z * w.x; acc[1][1] += h1.z * w.y; acc[1][2] += h1.z * w.z; acc[1][3] += h1.z * w.w;
        acc[2][0] += h2.z * w.x; acc[2][1] += h2.z * w.y; acc[2][2] += h2.z * w.z; acc[2][3] += h2.z * w.w;
        acc[3][0] += h3.z * w.x; acc[3][1] += h3.z * w.y; acc[3][2] += h3.z * w.z; acc[3][3] += h3.z * w.w;
        w = sW[(kk + 3) * 32 + tc];
        acc[0][0] += h0.w * w.x; acc[0][1] += h0.w * w.y; acc[0][2] += h0.w * w.z; acc[0][3] += h0.w * w.w;
        acc[1][0] += h1.w * w.x; acc[1][1] += h1.w * w.y; acc[1][2] += h1.w * w.z; acc[1][3] += h1.w * w.w;
        acc[2][0] += h2.w * w.x; acc[2][1] += h2.w * w.y; acc[2][2] += h2.w * w.z; acc[2][3] += h2.w * w.w;
        acc[3][0] += h3.w * w.x; acc[3][1] += h3.w * w.y; acc[3][2] += h3.w * w.z; acc[3][3] += h3.w * w.w;
    }
#pragma unroll
    for (int r = 0; r < 4; r++) {
        int node = nb + tr * 4 + r;
        if (node < NN) {
            float4 v = make_float4(acc[r][0], acc[r][1], acc[r][2], acc[r][3]);
            *(float4*)(T + (size_t)node * 1024 + cb * 128 + tc * 4) = v;
        }
    }
}

// ---------------- node linear: z = h@W_root + b_conv ; u = h@Bnn ----------------
__global__ void k_node_lin(const float* __restrict__ h, const float* __restrict__ Wr,
                           const float* __restrict__ bc, const float* __restrict__ bnn,
                           float* __restrict__ z, float* __restrict__ u) {
    __shared__ float sWr[H * H];
    __shared__ float sBn[H * H];
    int t = threadIdx.x;
    for (int j = t; j < H * H; j += 256) { sWr[j] = Wr[j]; sBn[j] = bnn[j]; }
    __syncthreads();
    int node = blockIdx.x * 8 + (t >> 5);
    int o = t & 31;
    if (node >= NN) return;
    const float* hr = h + node * H;
    float a = bc[o], bacc = 0.f;
#pragma unroll
    for (int i = 0; i < H; i++) {
        float hv = hr[i];
        a += hv * sWr[i * H + o];
        bacc += hv * sBn[i * H + o];
    }
    z[node * H + o] = a;
    u[node * H + o] = bacc;
}

// ---------------- edge message: m = u_src + ea_e . T_src ; atomic into agg[dst] ----------------
__global__ void k_edge_msg(const float* __restrict__ ea, const float* __restrict__ T,
                           const float* __restrict__ u, const int* __restrict__ src,
                           const int* __restrict__ dst, float* __restrict__ agg) {
    __shared__ float sea[8][32];
    int t = threadIdx.x;
    int eb = blockIdx.x * 8;
    {
        int e = eb + (t >> 5);
        if (e < NE) sea[t >> 5][t & 31] = ea[e * FE2 + (t & 31)];
    }
    __syncthreads();
    int e = eb + (t >> 5);
    int o = t & 31;
    if (e >= NE) return;
    int s = src[e], d = dst[e];
    const float* Tr = T + (size_t)s * 1024;
    float m = u[s * H + o];
    const float* sr = sea[t >> 5];
#pragma unroll
    for (int k = 0; k < 32; k++) m += sr[k] * Tr[k * 32 + o];
    atomicAdd(&agg[d * H + o], m);
}

// ---------------- z += agg ; accumulate per-channel sum & sumsq ----------------
__global__ void k_add_stats(float* __restrict__ z, const float* __restrict__ agg,
                            float* __restrict__ stats) {
    __shared__ float red[256];
    int t = threadIdx.x;
    float s = 0.f, s2 = 0.f;
    for (size_t idx = (size_t)blockIdx.x * 256 + t; idx < (size_t)NN * H;
         idx += (size_t)gridDim.x * 256) {
        float v = z[idx] + agg[idx];
        z[idx] = v;
        s += v;
        s2 += v * v;
    }
    red[t] = s;
    __syncthreads();
    for (int st = 128; st >= 32; st >>= 1) {
        if (t < st) red[t] += red[t + st];
        __syncthreads();
    }
    if (t < 32) atomicAdd(&stats[t], red[t]);
    __syncthreads();
    red[t] = s2;
    __syncthreads();
    for (int st = 128; st >= 32; st >>= 1) {
        if (t < st) red[t] += red[t + st];
        __syncthreads();
    }
    if (t < 32) atomicAdd(&stats[32 + t], red[t]);
}

// ---------------- BN apply + ReLU ----------------
__global__ void k_bn_apply(const float* __restrict__ z, const float* __restrict__ stats,
                           const float* __restrict__ gamma, const float* __restrict__ beta,
                           float* __restrict__ h) {
    int idx = blockIdx.x * 256 + threadIdx.x;
    if (idx >= NN * H) return;
    int o = idx & 31;
    const float invn = 1.0f / (float)NN;
    float mu = stats[o] * invn;
    float var = stats[32 + o] * invn - mu * mu;
    float v = (z[idx] - mu) * rsqrtf(var + EPSV) * gamma[o] + beta[o];
    h[idx] = v > 0.f ? v : 0.f;
}

// ---------------- pool: segment sums over graphs ----------------
__global__ void k_pool(const float* __restrict__ h, const int* __restrict__ batch,
                       float* __restrict__ gsum, float* __restrict__ cnt) {
    int idx = blockIdx.x * 256 + threadIdx.x;
    if (idx >= NN * H) return;
    int n = idx >> 5, o = idx & 31;
    int g = batch[n];
    atomicAdd(&gsum[g * H + o], h[idx]);
    if (o == 0) atomicAdd(&cnt[g], 1.f);
}

// ---------------- head: gx -> lin2 -> relu -> lin3 ----------------
__global__ void k_head(const float* __restrict__ gsum, const float* __restrict__ cnt,
                       const float* __restrict__ W2, const float* __restrict__ b2,
                       const float* __restrict__ W3, const float* __restrict__ b3,
                       float* __restrict__ out) {
    __shared__ float sW2[H * 16];
    __shared__ float sW3[16];
    __shared__ float sb2[16];
    int t = threadIdx.x;
    for (int j = t; j < H * 16; j += 256) sW2[j] = W2[j];
    if (t < 16) { sW3[t] = W3[t]; sb2[t] = b2[t]; }
    __syncthreads();
    int g = blockIdx.x * 256 + t;
    if (g >= NG) return;
    float inv = 1.0f / fmaxf(cnt[g], 1.0f);
    float gx[H];
#pragma unroll
    for (int i = 0; i < H; i++) gx[i] = gsum[g * H + i] * inv;
    float o3 = b3[0];
#pragma unroll
    for (int j = 0; j < 16; j++) {
        float hh = sb2[j];
#pragma unroll
        for (int i = 0; i < H; i++) hh += gx[i] * sW2[i * 16 + j];
        hh = hh > 0.f ? hh : 0.f;
        o3 += hh * sW3[j];
    }
    out[g] = o3;
}

extern "C" void kernel_launch(void* const* d_in, const int* in_sizes, int n_in,
                              void* d_out, int out_size, void* d_ws, size_t ws_size,
                              hipStream_t stream) {
    const float* x      = (const float*)d_in[0];
    const float* eattr  = (const float*)d_in[1];
    const float* W_node = (const float*)d_in[2];
    const float* b_node = (const float*)d_in[3];
    const float* W_edge = (const float*)d_in[4];
    const float* b_edge = (const float*)d_in[5];
    const float* W_nn   = (const float*)d_in[6];
    const float* b_nn   = (const float*)d_in[7];
    const float* W_root = (const float*)d_in[8];
    const float* b_conv = (const float*)d_in[9];
    const float* gamma  = (const float*)d_in[10];
    const float* beta   = (const float*)d_in[11];
    const float* W2     = (const float*)d_in[12];
    const float* b2     = (const float*)d_in[13];
    const float* W3     = (const float*)d_in[14];
    const float* b3     = (const float*)d_in[15];
    const int* eidx     = (const int*)d_in[16];
    const int* batch    = (const int*)d_in[17];
    const int* src = eidx;
    const int* dst = eidx + NE;
    float* out = (float*)d_out;

    float* ws = (float*)d_ws;
    float* h    = ws;                       // NN*32
    float* z    = h + (size_t)NN * H;       // NN*32
    float* u    = z + (size_t)NN * H;       // NN*32
    float* agg  = u + (size_t)NN * H;       // NN*32
    float* ea   = agg + (size_t)NN * H;     // NE*32
    float* Wt   = ea + (size_t)NE * FE2;    // 3*8*32*128
    float* stats = Wt + (size_t)NL * 8 * 32 * 128;  // 64
    float* gsum = stats + 64;               // NG*32
    float* cnt  = gsum + (size_t)NG * H;    // NG
    float* T    = cnt + NG;                 // NN*1024

    // prep repacked W_nn
    k_prep_wt<<<(NL * 8 * 32 * 128 + 255) / 256, 256, 0, stream>>>(W_nn, Wt);
    // embeddings
    k_node_emb<<<(NN + 7) / 8, 256, 0, stream>>>(x, W_node, b_node, h);
    k_edge_emb<<<(NE + 7) / 8, 256, 0, stream>>>(eattr, W_edge, b_edge, ea);

    for (int l = 0; l < NL; l++) {
        k_gemm_T<<<((NN + 31) / 32) * 8, 256, 0, stream>>>(h, Wt + (size_t)l * 8 * 32 * 128, T);
        k_node_lin<<<(NN + 7) / 8, 256, 0, stream>>>(h, W_root + l * H * H, b_conv + l * H,
                                                     b_nn + l * H * H, z, u);
        hipMemsetAsync(agg, 0, (size_t)NN * H * sizeof(float), stream);
        hipMemsetAsync(stats, 0, 64 * sizeof(float), stream);
        k_edge_msg<<<(NE + 7) / 8, 256, 0, stream>>>(ea, T, u, src, dst, agg);
        k_add_stats<<<512, 256, 0, stream>>>(z, agg, stats);
        k_bn_apply<<<(NN * H + 255) / 256, 256, 0, stream>>>(z, stats, gamma + l * H,
                                                             beta + l * H, h);
    }

    hipMemsetAsync(gsum, 0, (size_t)NG * H * sizeof(float), stream);
    hipMemsetAsync(cnt, 0, NG * sizeof(float), stream);
    k_pool<<<(NN * H + 255) / 256, 256, 0, stream>>>(h, batch, gsum, cnt);
    k_head<<<(NG + 255) / 256, 256, 0, stream>>>(gsum, cnt, W2, b2, W3, b3, out);
}